// Round 8
// baseline (177.323 us; speedup 1.0000x reference)
//
#include <hip/hip_runtime.h>
#include <math.h>

#define BB 32
#define NN 4096
#define DD 512
#define CC 5
#define SSEG 16   // 32*16 = 512 blocks = exactly 2 resident blocks/CU (launch_bounds 256,2)

// DPP-add step: v += dpp_permuted(v). bound_ctrl=1 -> 0 for lanes w/o source.
#define DPP_ADD(v, ctrl, rmask)                                                 \
    (v) += __int_as_float(__builtin_amdgcn_update_dpp(                          \
        0, __float_as_int(v), (ctrl), (rmask), 0xF, true))

// Canonical CDNA wave64 all-reduce via DPP only (no DS pipe), result made
// wave-uniform via readlane 63.
static __device__ __forceinline__ float wave_allreduce_add(float v)
{
    DPP_ADD(v, 0x111, 0xF);   // row_shr:1
    DPP_ADD(v, 0x112, 0xF);   // row_shr:2
    DPP_ADD(v, 0x114, 0xF);   // row_shr:4
    DPP_ADD(v, 0x118, 0xF);   // row_shr:8
    DPP_ADD(v, 0x142, 0xA);   // row_bcast:15 -> rows 1,3
    DPP_ADD(v, 0x143, 0xC);   // row_bcast:31 -> rows 2,3
    return __int_as_float(__builtin_amdgcn_readlane(__float_as_int(v), 63));
}

// All hot-loop bodies are macros over kernel-scope arrays with fully unrolled
// compile-time indices -> everything stays in VGPRs (R6 lesson: passing these
// arrays to functions took their address and spilled them to scratch).
#define LOADB(XA, XB, row)                                                      \
    {                                                                           \
        _Pragma("unroll")                                                       \
        for (int _r = 0; _r < 4; ++_r) {                                        \
            const float* _xr = xb_ + (size_t)((row) + _r) * DD;                 \
            XA[_r] = *reinterpret_cast<const float4*>(_xr + d0);                \
            XB[_r] = *reinterpret_cast<const float4*>(_xr + d1);                \
        }                                                                       \
    }

#define PROCB(XA, XB)                                                           \
    {                                                                           \
        float _e[4][CC];                                                        \
        _Pragma("unroll")                                                       \
        for (int _r = 0; _r < 4; ++_r) {                                        \
            const float _xv[8] = {XA[_r].x, XA[_r].y, XA[_r].z, XA[_r].w,       \
                                  XB[_r].x, XB[_r].y, XB[_r].z, XB[_r].w};      \
            _Pragma("unroll")                                                   \
            for (int _c = 0; _c < CC; ++_c) {                                   \
                float _s = 0.0f;                                                \
                _Pragma("unroll")                                               \
                for (int _j = 0; _j < 4; ++_j)                                  \
                    _s = fmaf(_xv[_j], wal[_j * CC + _c], _s);                  \
                _Pragma("unroll")                                               \
                for (int _j = 0; _j < 4; ++_j)                                  \
                    _s = fmaf(_xv[4 + _j], wah[_j * CC + _c], _s);              \
                _e[_r][_c] = _s;                                                \
            }                                                                   \
        }                                                                       \
        _Pragma("unroll")                                                       \
        for (int _r = 0; _r < 4; ++_r)                                          \
            _Pragma("unroll")                                                   \
            for (int _c = 0; _c < CC; ++_c)                                     \
                _e[_r][_c] = wave_allreduce_add(_e[_r][_c]);                    \
        float _mb[CC];                                                          \
        _Pragma("unroll")                                                       \
        for (int _c = 0; _c < CC; ++_c)                                         \
            _mb[_c] = fmaxf(fmaxf(_e[0][_c], _e[1][_c]),                        \
                            fmaxf(_e[2][_c], _e[3][_c]));                       \
        bool _raise = false;                                                    \
        _Pragma("unroll")                                                       \
        for (int _c = 0; _c < CC; ++_c) _raise = _raise || (_mb[_c] > m[_c]);   \
        if (__ballot(_raise) != 0ull) {                                         \
            _Pragma("unroll")                                                   \
            for (int _c = 0; _c < CC; ++_c) {                                   \
                const float _mn = fmaxf(m[_c], _mb[_c]);                        \
                const float _sc = __expf(m[_c] - _mn);                          \
                l[_c] *= _sc;                                                   \
                _Pragma("unroll")                                               \
                for (int _j = 0; _j < 8; ++_j) acc[_c][_j] *= _sc;              \
                m[_c] = _mn;                                                    \
            }                                                                   \
        }                                                                       \
        _Pragma("unroll")                                                       \
        for (int _r = 0; _r < 4; ++_r) {                                        \
            const float _xv[8] = {XA[_r].x, XA[_r].y, XA[_r].z, XA[_r].w,       \
                                  XB[_r].x, XB[_r].y, XB[_r].z, XB[_r].w};      \
            _Pragma("unroll")                                                   \
            for (int _c = 0; _c < CC; ++_c) {                                   \
                const float _p = __expf(_e[_r][_c] - m[_c]);                    \
                l[_c] += _p;                                                    \
                _Pragma("unroll")                                               \
                for (int _j = 0; _j < 8; ++_j)                                  \
                    acc[_c][_j] = fmaf(_p, _xv[_j], acc[_c][_j]);               \
            }                                                                   \
        }                                                                       \
    }

// Fused kernel: streams x once (ping-pong 4-row batches, peeled tail so no
// dead prefetch), writes per-(b,seg) partials, then the LAST block to finish
// each b runs the cross-segment combine + epilogue (split-k fixup).
__global__ __launch_bounds__(256, 2)
void capsule_fused(const float* __restrict__ x, const float* __restrict__ Wa,
                   const float* __restrict__ lin_w, const float* __restrict__ lin_b,
                   float* __restrict__ acc_ws, float* __restrict__ ml_ws,
                   int* __restrict__ cnt,
                   float* __restrict__ p_out, float* __restrict__ v_out,
                   float* __restrict__ r_out)
{
    const int blk  = blockIdx.x;
    const int b    = blk / SSEG;
    const int seg  = blk % SSEG;
    const int tid  = threadIdx.x;
    const int lane = tid & 63;
    const int wid  = tid >> 6;   // 0..3

    const int d0 = lane * 4;
    const int d1 = 256 + lane * 4;

    // W_alpha fragments (4 d's x 5 c's per half), float4 loads
    float wal[20], wah[20];
    {
        const float4* pl = reinterpret_cast<const float4*>(Wa + d0 * CC);
        const float4* ph = reinterpret_cast<const float4*>(Wa + d1 * CC);
#pragma unroll
        for (int q = 0; q < 5; ++q) {
            float4 a = pl[q];
            wal[q * 4 + 0] = a.x; wal[q * 4 + 1] = a.y;
            wal[q * 4 + 2] = a.z; wal[q * 4 + 3] = a.w;
            float4 b4 = ph[q];
            wah[q * 4 + 0] = b4.x; wah[q * 4 + 1] = b4.y;
            wah[q * 4 + 2] = b4.z; wah[q * 4 + 3] = b4.w;
        }
    }

    float acc[CC][8];
    float m[CC], l[CC];
#pragma unroll
    for (int c = 0; c < CC; ++c) {
        m[c] = -INFINITY;
        l[c] = 0.0f;
#pragma unroll
        for (int j = 0; j < 8; ++j) acc[c][j] = 0.0f;
    }

    // segment = 256 rows; wave slice = 64 rows = 16 batches of 4 (exact)
    const int rs  = seg * (NN / SSEG);
    const int ws_ = rs + wid * (NN / SSEG / 4);
    const int we_ = ws_ + (NN / SSEG / 4);

    const float* xb_ = x + (size_t)b * NN * DD;

    float4 xaA[4], xbA[4], xaB[4], xbB[4];
    LOADB(xaA, xbA, ws_);
    int i0 = ws_;
    for (; i0 + 8 < we_; i0 += 8) {        // last pair peeled (no dead prefetch)
        LOADB(xaB, xbB, i0 + 4);
        PROCB(xaA, xbA);
        LOADB(xaA, xbA, i0 + 8);
        PROCB(xaB, xbB);
    }
    LOADB(xaB, xbB, i0 + 4);
    PROCB(xaA, xbA);
    PROCB(xaB, xbB);

    // ---- combine the 4 waves ----
    __shared__ float s_ml[4][CC][2];
    __shared__ float s_acc[CC][DD];   // 10 KB
    __shared__ float s_red[4];
    __shared__ int   s_last;

    if (lane == 0) {
#pragma unroll
        for (int c = 0; c < CC; ++c) {
            s_ml[wid][c][0] = m[c];
            s_ml[wid][c][1] = l[c];
        }
    }
    __syncthreads();

    float mb2[CC], lb2[CC], cw[CC];
#pragma unroll
    for (int c = 0; c < CC; ++c) {
        float mm = s_ml[0][c][0];
#pragma unroll
        for (int w = 1; w < 4; ++w) mm = fmaxf(mm, s_ml[w][c][0]);
        mb2[c] = mm;
        float ll = 0.0f;
#pragma unroll
        for (int w = 0; w < 4; ++w) ll += __expf(s_ml[w][c][0] - mm) * s_ml[w][c][1];
        lb2[c] = ll;
        cw[c] = __expf(s_ml[wid][c][0] - mm);
    }

    for (int w = 0; w < 4; ++w) {
        if (wid == w) {
#pragma unroll
            for (int c = 0; c < CC; ++c) {
#pragma unroll
                for (int j = 0; j < 8; ++j) {
                    const int d = (j < 4) ? (d0 + j) : (d1 + j - 4);
                    const float v = acc[c][j] * cw[c];
                    if (w == 0) s_acc[c][d] = v;
                    else        s_acc[c][d] += v;
                }
            }
        }
        __syncthreads();
    }

    // write block partials to workspace (float4)
    float4* accp = reinterpret_cast<float4*>(acc_ws + (size_t)blk * CC * DD);
    const float4* sa = reinterpret_cast<const float4*>(&s_acc[0][0]);
    for (int idx = tid; idx < CC * DD / 4; idx += 256) accp[idx] = sa[idx];
    if (tid < CC) {
        ml_ws[((size_t)blk * CC + tid) * 2 + 0] = mb2[tid];
        ml_ws[((size_t)blk * CC + tid) * 2 + 1] = lb2[tid];
    }

    // ---- last-block-per-b finisher (split-k fixup) ----
    __threadfence();                      // release: partials visible device-wide
    __syncthreads();
    if (tid == 0) s_last = (atomicAdd(&cnt[b], 1) == SSEG - 1) ? 1 : 0;
    __syncthreads();
    if (!s_last) return;
    __threadfence();                      // acquire

    for (int c = 0; c < CC; ++c) {
        const int bc = b * CC + c;
        float mg = -INFINITY;
        for (int s = 0; s < SSEG; ++s)
            mg = fmaxf(mg, ml_ws[(((size_t)b * SSEG + s) * CC + c) * 2]);
        float lg = 0.0f;
        for (int s = 0; s < SSEG; ++s) {
            const float mw = ml_ws[(((size_t)b * SSEG + s) * CC + c) * 2];
            const float lw = ml_ws[(((size_t)b * SSEG + s) * CC + c) * 2 + 1];
            lg += __expf(mw - mg) * lw;
        }
        const float inv_l = 1.0f / lg;

        float v0 = 0.0f, v1 = 0.0f;
        for (int s = 0; s < SSEG; ++s) {
            const float mw = ml_ws[(((size_t)b * SSEG + s) * CC + c) * 2];
            const float w  = __expf(mw - mg);
            const float* ap = acc_ws + (((size_t)b * SSEG + s) * CC + c) * DD;
            v0 = fmaf(w, ap[tid], v0);
            v1 = fmaf(w, ap[tid + 256], v1);
        }
        v0 *= inv_l;
        v1 *= inv_l;

        v_out[(size_t)bc * DD + tid]       = v0;
        v_out[(size_t)bc * DD + tid + 256] = v1;

        float part = wave_allreduce_add(v0 * lin_w[tid] + v1 * lin_w[tid + 256]);
        if (lane == 0) s_red[wid] = part;
        __syncthreads();
        const float p = tanhf(s_red[0] + s_red[1] + s_red[2] + s_red[3] + lin_b[0]);
        if (tid == 0) p_out[bc] = p;
        r_out[(size_t)bc * DD + tid]       = p * v0;
        r_out[(size_t)bc * DD + tid + 256] = p * v1;
        __syncthreads();   // s_red reused next c
    }
}

extern "C" void kernel_launch(void* const* d_in, const int* in_sizes, int n_in,
                              void* d_out, int out_size, void* d_ws, size_t ws_size,
                              hipStream_t stream) {
    const float* x   = (const float*)d_in[0];
    const float* Wa  = (const float*)d_in[1];
    const float* lw  = (const float*)d_in[2];
    const float* lb  = (const float*)d_in[3];

    float* out   = (float*)d_out;
    float* p_out = out;                       // (B, C)
    float* v_out = out + BB * CC;             // (B, C, D)
    float* r_out = v_out + BB * CC * DD;      // (B, C, D)

    float* acc_ws = (float*)d_ws;                           // B*SSEG*C*D floats
    float* ml_ws  = acc_ws + (size_t)BB * SSEG * CC * DD;   // B*SSEG*C*2 floats
    int*   cnt    = (int*)(ml_ws + (size_t)BB * SSEG * CC * 2);  // B ints

    hipMemsetAsync(cnt, 0, BB * sizeof(int), stream);

    capsule_fused<<<dim3(BB * SSEG), dim3(256), 0, stream>>>(
        x, Wa, lw, lb, acc_ws, ml_ws, cnt, p_out, v_out, r_out);
}

// Round 9
// 60.929 us; speedup vs baseline: 2.9103x; 2.9103x over previous
//
#include <hip/hip_runtime.h>
#include <math.h>

#define BB 32
#define NN 4096
#define DD 512
#define CC 5
#define SSEG 16   // 32*16 = 512 blocks = exactly 2 resident blocks/CU (launch_bounds 256,2)

// DPP-add step: v += dpp_permuted(v). bound_ctrl=1 -> 0 for lanes w/o source.
#define DPP_ADD(v, ctrl, rmask)                                                 \
    (v) += __int_as_float(__builtin_amdgcn_update_dpp(                          \
        0, __float_as_int(v), (ctrl), (rmask), 0xF, true))

// Canonical CDNA wave64 all-reduce via DPP only (no DS pipe), result made
// wave-uniform via readlane 63.
static __device__ __forceinline__ float wave_allreduce_add(float v)
{
    DPP_ADD(v, 0x111, 0xF);   // row_shr:1
    DPP_ADD(v, 0x112, 0xF);   // row_shr:2
    DPP_ADD(v, 0x114, 0xF);   // row_shr:4
    DPP_ADD(v, 0x118, 0xF);   // row_shr:8
    DPP_ADD(v, 0x142, 0xA);   // row_bcast:15 -> rows 1,3
    DPP_ADD(v, 0x143, 0xC);   // row_bcast:31 -> rows 2,3
    return __int_as_float(__builtin_amdgcn_readlane(__float_as_int(v), 63));
}

// Hot-loop bodies are macros over kernel-scope arrays with fully unrolled
// compile-time indices -> everything stays in VGPRs (R6/R8 lesson).
#define LOADB(XA, XB, row)                                                      \
    {                                                                           \
        _Pragma("unroll")                                                       \
        for (int _r = 0; _r < 4; ++_r) {                                        \
            const float* _xr = xb_ + (size_t)((row) + _r) * DD;                 \
            XA[_r] = *reinterpret_cast<const float4*>(_xr + d0);                \
            XB[_r] = *reinterpret_cast<const float4*>(_xr + d1);                \
        }                                                                       \
    }

#define PROCB(XA, XB)                                                           \
    {                                                                           \
        float _e[4][CC];                                                        \
        _Pragma("unroll")                                                       \
        for (int _r = 0; _r < 4; ++_r) {                                        \
            const float _xv[8] = {XA[_r].x, XA[_r].y, XA[_r].z, XA[_r].w,       \
                                  XB[_r].x, XB[_r].y, XB[_r].z, XB[_r].w};      \
            _Pragma("unroll")                                                   \
            for (int _c = 0; _c < CC; ++_c) {                                   \
                float _s = 0.0f;                                                \
                _Pragma("unroll")                                               \
                for (int _j = 0; _j < 4; ++_j)                                  \
                    _s = fmaf(_xv[_j], wal[_j * CC + _c], _s);                  \
                _Pragma("unroll")                                               \
                for (int _j = 0; _j < 4; ++_j)                                  \
                    _s = fmaf(_xv[4 + _j], wah[_j * CC + _c], _s);              \
                _e[_r][_c] = _s;                                                \
            }                                                                   \
        }                                                                       \
        _Pragma("unroll")                                                       \
        for (int _r = 0; _r < 4; ++_r)                                          \
            _Pragma("unroll")                                                   \
            for (int _c = 0; _c < CC; ++_c)                                     \
                _e[_r][_c] = wave_allreduce_add(_e[_r][_c]);                    \
        float _mb[CC];                                                          \
        _Pragma("unroll")                                                       \
        for (int _c = 0; _c < CC; ++_c)                                         \
            _mb[_c] = fmaxf(fmaxf(_e[0][_c], _e[1][_c]),                        \
                            fmaxf(_e[2][_c], _e[3][_c]));                       \
        bool _raise = false;                                                    \
        _Pragma("unroll")                                                       \
        for (int _c = 0; _c < CC; ++_c) _raise = _raise || (_mb[_c] > m[_c]);   \
        if (__ballot(_raise) != 0ull) {                                         \
            _Pragma("unroll")                                                   \
            for (int _c = 0; _c < CC; ++_c) {                                   \
                const float _mn = fmaxf(m[_c], _mb[_c]);                        \
                const float _sc = __expf(m[_c] - _mn);                          \
                l[_c] *= _sc;                                                   \
                _Pragma("unroll")                                               \
                for (int _j = 0; _j < 8; ++_j) acc[_c][_j] *= _sc;              \
                m[_c] = _mn;                                                    \
            }                                                                   \
        }                                                                       \
        _Pragma("unroll")                                                       \
        for (int _r = 0; _r < 4; ++_r) {                                        \
            const float _xv[8] = {XA[_r].x, XA[_r].y, XA[_r].z, XA[_r].w,       \
                                  XB[_r].x, XB[_r].y, XB[_r].z, XB[_r].w};      \
            _Pragma("unroll")                                                   \
            for (int _c = 0; _c < CC; ++_c) {                                   \
                const float _p = __expf(_e[_r][_c] - m[_c]);                    \
                l[_c] += _p;                                                    \
                _Pragma("unroll")                                               \
                for (int _j = 0; _j < 8; ++_j)                                  \
                    acc[_c][_j] = fmaf(_p, _xv[_j], acc[_c][_j]);               \
            }                                                                   \
        }                                                                       \
    }

// Pass 1: stream x once. Block = (b, segment of 256 rows). 4 waves; each wave
// owns 64 contiguous rows = 16 batches of 4, processed with a TRIPLE-buffered
// register pipeline (~16 KB/wave outstanding during compute).
__global__ __launch_bounds__(256, 2)
void capsule_pass1(const float* __restrict__ x, const float* __restrict__ Wa,
                   float* __restrict__ acc_ws, float* __restrict__ ml_ws)
{
    const int blk  = blockIdx.x;
    const int b    = blk / SSEG;
    const int seg  = blk % SSEG;
    const int tid  = threadIdx.x;
    const int lane = tid & 63;
    const int wid  = tid >> 6;   // 0..3

    const int d0 = lane * 4;
    const int d1 = 256 + lane * 4;

    // W_alpha fragments (4 d's x 5 c's per half), float4 loads
    float wal[20], wah[20];
    {
        const float4* pl = reinterpret_cast<const float4*>(Wa + d0 * CC);
        const float4* ph = reinterpret_cast<const float4*>(Wa + d1 * CC);
#pragma unroll
        for (int q = 0; q < 5; ++q) {
            float4 a = pl[q];
            wal[q * 4 + 0] = a.x; wal[q * 4 + 1] = a.y;
            wal[q * 4 + 2] = a.z; wal[q * 4 + 3] = a.w;
            float4 b4 = ph[q];
            wah[q * 4 + 0] = b4.x; wah[q * 4 + 1] = b4.y;
            wah[q * 4 + 2] = b4.z; wah[q * 4 + 3] = b4.w;
        }
    }

    float acc[CC][8];
    float m[CC], l[CC];
#pragma unroll
    for (int c = 0; c < CC; ++c) {
        m[c] = -INFINITY;
        l[c] = 0.0f;
#pragma unroll
        for (int j = 0; j < 8; ++j) acc[c][j] = 0.0f;
    }

    // segment = 256 rows; wave slice = 64 rows = 16 batches of 4 (exact)
    const int rs  = seg * (NN / SSEG);
    const int ws_ = rs + wid * (NN / SSEG / 4);

    const float* xb_ = x + (size_t)b * NN * DD;

    // triple-buffered pipeline over 16 batches: loads run 2 batches ahead
    float4 xaA[4], xbA[4], xaB[4], xbB[4], xaC[4], xbC[4];
    LOADB(xaA, xbA, ws_);         // batch 0
    LOADB(xaB, xbB, ws_ + 4);     // batch 1
    int i0 = ws_;
    for (int j = 0; j < 5; ++j, i0 += 12) {
        LOADB(xaC, xbC, i0 + 8);
        PROCB(xaA, xbA);
        LOADB(xaA, xbA, i0 + 12);
        PROCB(xaB, xbB);
        const int nxt = (j < 4) ? (i0 + 16) : i0;   // j=4: clamped dead load (DCE)
        LOADB(xaB, xbB, nxt);
        PROCB(xaC, xbC);
    }
    PROCB(xaA, xbA);              // batch 15

    // ---- combine the 4 waves ----
    __shared__ float s_ml[4][CC][2];
    __shared__ float s_acc[CC][DD];   // 10 KB

    if (lane == 0) {
#pragma unroll
        for (int c = 0; c < CC; ++c) {
            s_ml[wid][c][0] = m[c];
            s_ml[wid][c][1] = l[c];
        }
    }
    __syncthreads();

    float mb2[CC], lb2[CC], cw[CC];
#pragma unroll
    for (int c = 0; c < CC; ++c) {
        float mm = s_ml[0][c][0];
#pragma unroll
        for (int w = 1; w < 4; ++w) mm = fmaxf(mm, s_ml[w][c][0]);
        mb2[c] = mm;
        float ll = 0.0f;
#pragma unroll
        for (int w = 0; w < 4; ++w) ll += __expf(s_ml[w][c][0] - mm) * s_ml[w][c][1];
        lb2[c] = ll;
        cw[c] = __expf(s_ml[wid][c][0] - mm);
    }

    for (int w = 0; w < 4; ++w) {
        if (wid == w) {
#pragma unroll
            for (int c = 0; c < CC; ++c) {
#pragma unroll
                for (int j = 0; j < 8; ++j) {
                    const int d = (j < 4) ? (d0 + j) : (d1 + j - 4);
                    const float v = acc[c][j] * cw[c];
                    if (w == 0) s_acc[c][d] = v;
                    else        s_acc[c][d] += v;
                }
            }
        }
        __syncthreads();
    }

    // write block partials to workspace (float4)
    float4* accp = reinterpret_cast<float4*>(acc_ws + (size_t)blk * CC * DD);
    const float4* sa = reinterpret_cast<const float4*>(&s_acc[0][0]);
    for (int idx = tid; idx < CC * DD / 4; idx += 256) accp[idx] = sa[idx];
    if (tid < CC) {
        ml_ws[((size_t)blk * CC + tid) * 2 + 0] = mb2[tid];
        ml_ws[((size_t)blk * CC + tid) * 2 + 1] = lb2[tid];
    }
}

// Pass 2: one block per (b,c). Combine SSEG segment partials, normalize,
// epilogue p = tanh(v.w + b), r = p*v, write all three outputs.
__global__ __launch_bounds__(256)
void capsule_pass2(const float* __restrict__ acc_ws, const float* __restrict__ ml_ws,
                   const float* __restrict__ lin_w, const float* __restrict__ lin_b,
                   float* __restrict__ p_out, float* __restrict__ v_out,
                   float* __restrict__ r_out)
{
    const int bc  = blockIdx.x;          // 0..B*C-1
    const int b   = bc / CC;
    const int c   = bc % CC;
    const int tid = threadIdx.x;

    __shared__ float s_w[SSEG];
    __shared__ float s_red[4];
    __shared__ float s_p;

    float mg = -INFINITY;
    for (int s = 0; s < SSEG; ++s)
        mg = fmaxf(mg, ml_ws[(((size_t)b * SSEG + s) * CC + c) * 2]);
    float lg = 0.0f;
    for (int s = 0; s < SSEG; ++s) {
        const float mw = ml_ws[(((size_t)b * SSEG + s) * CC + c) * 2];
        const float lw = ml_ws[(((size_t)b * SSEG + s) * CC + c) * 2 + 1];
        const float w  = __expf(mw - mg);
        lg += w * lw;
        if (tid == 0) s_w[s] = w;
    }
    __syncthreads();

    const float inv_l = 1.0f / lg;
    float v0 = 0.0f, v1 = 0.0f;
    for (int s = 0; s < SSEG; ++s) {
        const float* ap = acc_ws + (((size_t)b * SSEG + s) * CC + c) * DD;
        const float w = s_w[s];
        v0 = fmaf(w, ap[tid], v0);
        v1 = fmaf(w, ap[tid + 256], v1);
    }
    v0 *= inv_l;
    v1 *= inv_l;

    v_out[(size_t)bc * DD + tid]       = v0;
    v_out[(size_t)bc * DD + tid + 256] = v1;

    float part = v0 * lin_w[tid] + v1 * lin_w[tid + 256];
#pragma unroll
    for (int off = 1; off < 64; off <<= 1) part += __shfl_xor(part, off, 64);
    if ((tid & 63) == 0) s_red[tid >> 6] = part;
    __syncthreads();
    if (tid == 0) {
        const float dot = s_red[0] + s_red[1] + s_red[2] + s_red[3] + lin_b[0];
        const float p = tanhf(dot);
        s_p = p;
        p_out[bc] = p;
    }
    __syncthreads();
    const float p = s_p;
    r_out[(size_t)bc * DD + tid]       = p * v0;
    r_out[(size_t)bc * DD + tid + 256] = p * v1;
}

extern "C" void kernel_launch(void* const* d_in, const int* in_sizes, int n_in,
                              void* d_out, int out_size, void* d_ws, size_t ws_size,
                              hipStream_t stream) {
    const float* x   = (const float*)d_in[0];
    const float* Wa  = (const float*)d_in[1];
    const float* lw  = (const float*)d_in[2];
    const float* lb  = (const float*)d_in[3];

    float* out   = (float*)d_out;
    float* p_out = out;                       // (B, C)
    float* v_out = out + BB * CC;             // (B, C, D)
    float* r_out = v_out + BB * CC * DD;      // (B, C, D)

    float* acc_ws = (float*)d_ws;                           // B*SSEG*C*D floats
    float* ml_ws  = acc_ws + (size_t)BB * SSEG * CC * DD;   // B*SSEG*C*2 floats

    capsule_pass1<<<dim3(BB * SSEG), dim3(256), 0, stream>>>(x, Wa, acc_ws, ml_ws);
    capsule_pass2<<<dim3(BB * CC), dim3(256), 0, stream>>>(acc_ws, ml_ws, lw, lb,
                                                           p_out, v_out, r_out);
}

// Round 10
// 60.318 us; speedup vs baseline: 2.9398x; 1.0101x over previous
//
#include <hip/hip_runtime.h>
#include <math.h>

#define BB 32
#define NN 4096
#define DD 512
#define CC 5
#define SSEG 24   // 32*24 = 768 blocks = exactly 3 resident blocks/CU (launch_bounds 256,3)

// DPP-add step: v += dpp_permuted(v). bound_ctrl=1 -> 0 for lanes w/o source.
#define DPP_ADD(v, ctrl, rmask)                                                 \
    (v) += __int_as_float(__builtin_amdgcn_update_dpp(                          \
        0, __float_as_int(v), (ctrl), (rmask), 0xF, true))

// Canonical CDNA wave64 all-reduce via DPP only (no DS pipe), result made
// wave-uniform via readlane 63.
static __device__ __forceinline__ float wave_allreduce_add(float v)
{
    DPP_ADD(v, 0x111, 0xF);   // row_shr:1
    DPP_ADD(v, 0x112, 0xF);   // row_shr:2
    DPP_ADD(v, 0x114, 0xF);   // row_shr:4
    DPP_ADD(v, 0x118, 0xF);   // row_shr:8
    DPP_ADD(v, 0x142, 0xA);   // row_bcast:15 -> rows 1,3
    DPP_ADD(v, 0x143, 0xC);   // row_bcast:31 -> rows 2,3
    return __int_as_float(__builtin_amdgcn_readlane(__float_as_int(v), 63));
}

// Hot-loop bodies are macros over kernel-scope arrays with fully unrolled
// compile-time indices -> everything stays in VGPRs (R6/R8 lesson: never pass
// these arrays to functions; never fuse extra phases into this kernel).
#define LOAD2(XA, XB, row)                                                      \
    {                                                                           \
        _Pragma("unroll")                                                       \
        for (int _r = 0; _r < 2; ++_r) {                                        \
            const float* _xr = xb_ + (size_t)((row) + _r) * DD;                 \
            XA[_r] = *reinterpret_cast<const float4*>(_xr + d0);                \
            XB[_r] = *reinterpret_cast<const float4*>(_xr + d1);                \
        }                                                                       \
    }

#define PROC2(XA, XB)                                                           \
    {                                                                           \
        float _e[2][CC];                                                        \
        _Pragma("unroll")                                                       \
        for (int _r = 0; _r < 2; ++_r) {                                        \
            const float _xv[8] = {XA[_r].x, XA[_r].y, XA[_r].z, XA[_r].w,       \
                                  XB[_r].x, XB[_r].y, XB[_r].z, XB[_r].w};      \
            _Pragma("unroll")                                                   \
            for (int _c = 0; _c < CC; ++_c) {                                   \
                float _s = 0.0f;                                                \
                _Pragma("unroll")                                               \
                for (int _j = 0; _j < 4; ++_j)                                  \
                    _s = fmaf(_xv[_j], wal[_j * CC + _c], _s);                  \
                _Pragma("unroll")                                               \
                for (int _j = 0; _j < 4; ++_j)                                  \
                    _s = fmaf(_xv[4 + _j], wah[_j * CC + _c], _s);              \
                _e[_r][_c] = _s;                                                \
            }                                                                   \
        }                                                                       \
        _Pragma("unroll")                                                       \
        for (int _r = 0; _r < 2; ++_r)                                          \
            _Pragma("unroll")                                                   \
            for (int _c = 0; _c < CC; ++_c)                                     \
                _e[_r][_c] = wave_allreduce_add(_e[_r][_c]);                    \
        float _mb[CC];                                                          \
        _Pragma("unroll")                                                       \
        for (int _c = 0; _c < CC; ++_c)                                         \
            _mb[_c] = fmaxf(_e[0][_c], _e[1][_c]);                              \
        bool _raise = false;                                                    \
        _Pragma("unroll")                                                       \
        for (int _c = 0; _c < CC; ++_c) _raise = _raise || (_mb[_c] > m[_c]);   \
        if (__ballot(_raise) != 0ull) {                                         \
            _Pragma("unroll")                                                   \
            for (int _c = 0; _c < CC; ++_c) {                                   \
                const float _mn = fmaxf(m[_c], _mb[_c]);                        \
                const float _sc = __expf(m[_c] - _mn);                          \
                l[_c] *= _sc;                                                   \
                _Pragma("unroll")                                               \
                for (int _j = 0; _j < 8; ++_j) acc[_c][_j] *= _sc;              \
                m[_c] = _mn;                                                    \
            }                                                                   \
        }                                                                       \
        _Pragma("unroll")                                                       \
        for (int _r = 0; _r < 2; ++_r) {                                        \
            const float _xv[8] = {XA[_r].x, XA[_r].y, XA[_r].z, XA[_r].w,       \
                                  XB[_r].x, XB[_r].y, XB[_r].z, XB[_r].w};      \
            _Pragma("unroll")                                                   \
            for (int _c = 0; _c < CC; ++_c) {                                   \
                const float _p = __expf(_e[_r][_c] - m[_c]);                    \
                l[_c] += _p;                                                    \
                _Pragma("unroll")                                               \
                for (int _j = 0; _j < 8; ++_j)                                  \
                    acc[_c][_j] = fmaf(_p, _xv[_j], acc[_c][_j]);               \
            }                                                                   \
        }                                                                       \
    }

// Pass 1: stream x once. Block = (b, segment of ~170 rows). 4 waves; each
// wave owns a contiguous ~42-row slice processed as ping-pong 2-row batches
// (depth-2 prefetch) + optional single-row remainder. 12 waves/CU resident.
__global__ __launch_bounds__(256, 3)
void capsule_pass1(const float* __restrict__ x, const float* __restrict__ Wa,
                   float* __restrict__ acc_ws, float* __restrict__ ml_ws)
{
    const int blk  = blockIdx.x;
    const int b    = blk / SSEG;
    const int seg  = blk % SSEG;
    const int tid  = threadIdx.x;
    const int lane = tid & 63;
    const int wid  = tid >> 6;   // 0..3

    const int d0 = lane * 4;
    const int d1 = 256 + lane * 4;

    // W_alpha fragments (4 d's x 5 c's per half), float4 loads
    float wal[20], wah[20];
    {
        const float4* pl = reinterpret_cast<const float4*>(Wa + d0 * CC);
        const float4* ph = reinterpret_cast<const float4*>(Wa + d1 * CC);
#pragma unroll
        for (int q = 0; q < 5; ++q) {
            float4 a = pl[q];
            wal[q * 4 + 0] = a.x; wal[q * 4 + 1] = a.y;
            wal[q * 4 + 2] = a.z; wal[q * 4 + 3] = a.w;
            float4 b4 = ph[q];
            wah[q * 4 + 0] = b4.x; wah[q * 4 + 1] = b4.y;
            wah[q * 4 + 2] = b4.z; wah[q * 4 + 3] = b4.w;
        }
    }

    float acc[CC][8];
    float m[CC], l[CC];
#pragma unroll
    for (int c = 0; c < CC; ++c) {
        m[c] = -INFINITY;
        l[c] = 0.0f;
#pragma unroll
        for (int j = 0; j < 8; ++j) acc[c][j] = 0.0f;
    }

    // segment rows [rs, re), uneven split via integer division
    const int rs = (seg * NN) / SSEG;
    const int re = ((seg + 1) * NN) / SSEG;
    const int nrows = re - rs;
    // wave's contiguous slice
    const int ws_ = rs + (wid * nrows) / 4;
    const int we_ = rs + ((wid + 1) * nrows) / 4;

    const float* xb_ = x + (size_t)b * NN * DD;

    int i0 = ws_;
    const int cnt = we_ - ws_;
    const int nb  = cnt >> 1;          // full 2-row batches (>=21 here)

    float4 xaA[2], xbA[2], xaB[2], xbB[2];
    if (nb > 0) {
        LOAD2(xaA, xbA, i0);
        int k = 0;
        for (; k + 2 < nb; k += 2, i0 += 4) {
            LOAD2(xaB, xbB, i0 + 2);
            PROC2(xaA, xbA);
            LOAD2(xaA, xbA, i0 + 4);
            PROC2(xaB, xbB);
        }
        if (nb - k == 2) {
            LOAD2(xaB, xbB, i0 + 2);
            PROC2(xaA, xbA);
            PROC2(xaB, xbB);
            i0 += 4;
        } else {
            PROC2(xaA, xbA);
            i0 += 2;
        }
    }

    // single-row remainder (cnt odd)
    if (cnt & 1) {
        const float* xr = xb_ + (size_t)i0 * DD;
        const float4 xa = *reinterpret_cast<const float4*>(xr + d0);
        const float4 xb4 = *reinterpret_cast<const float4*>(xr + d1);
        const float xv[8] = {xa.x, xa.y, xa.z, xa.w, xb4.x, xb4.y, xb4.z, xb4.w};

        float e[CC];
#pragma unroll
        for (int c = 0; c < CC; ++c) {
            float s = 0.0f;
#pragma unroll
            for (int j = 0; j < 4; ++j) s = fmaf(xv[j], wal[j * CC + c], s);
#pragma unroll
            for (int j = 0; j < 4; ++j) s = fmaf(xv[4 + j], wah[j * CC + c], s);
            e[c] = wave_allreduce_add(s);
        }
#pragma unroll
        for (int c = 0; c < CC; ++c) {
            if (e[c] > m[c]) {
                const float sc = __expf(m[c] - e[c]);
                l[c] = l[c] * sc + 1.0f;
#pragma unroll
                for (int j = 0; j < 8; ++j) acc[c][j] = fmaf(acc[c][j], sc, xv[j]);
                m[c] = e[c];
            } else {
                const float p = __expf(e[c] - m[c]);
                l[c] += p;
#pragma unroll
                for (int j = 0; j < 8; ++j) acc[c][j] = fmaf(p, xv[j], acc[c][j]);
            }
        }
    }

    // ---- combine the 4 waves ----
    __shared__ float s_ml[4][CC][2];
    __shared__ float s_acc[CC][DD];   // 10 KB

    if (lane == 0) {
#pragma unroll
        for (int c = 0; c < CC; ++c) {
            s_ml[wid][c][0] = m[c];
            s_ml[wid][c][1] = l[c];
        }
    }
    __syncthreads();

    float mb2[CC], lb2[CC], cw[CC];
#pragma unroll
    for (int c = 0; c < CC; ++c) {
        float mm = s_ml[0][c][0];
#pragma unroll
        for (int w = 1; w < 4; ++w) mm = fmaxf(mm, s_ml[w][c][0]);
        mb2[c] = mm;
        float ll = 0.0f;
#pragma unroll
        for (int w = 0; w < 4; ++w) ll += __expf(s_ml[w][c][0] - mm) * s_ml[w][c][1];
        lb2[c] = ll;
        cw[c] = __expf(s_ml[wid][c][0] - mm);
    }

    for (int w = 0; w < 4; ++w) {
        if (wid == w) {
#pragma unroll
            for (int c = 0; c < CC; ++c) {
#pragma unroll
                for (int j = 0; j < 8; ++j) {
                    const int d = (j < 4) ? (d0 + j) : (d1 + j - 4);
                    const float v = acc[c][j] * cw[c];
                    if (w == 0) s_acc[c][d] = v;
                    else        s_acc[c][d] += v;
                }
            }
        }
        __syncthreads();
    }

    // write block partials to workspace (float4)
    float4* accp = reinterpret_cast<float4*>(acc_ws + (size_t)blk * CC * DD);
    const float4* sa = reinterpret_cast<const float4*>(&s_acc[0][0]);
    for (int idx = tid; idx < CC * DD / 4; idx += 256) accp[idx] = sa[idx];
    if (tid < CC) {
        ml_ws[((size_t)blk * CC + tid) * 2 + 0] = mb2[tid];
        ml_ws[((size_t)blk * CC + tid) * 2 + 1] = lb2[tid];
    }
}

// Pass 2: one block per (b,c). Combine SSEG segment partials, normalize,
// epilogue p = tanh(v.w + b), r = p*v, write all three outputs.
__global__ __launch_bounds__(256)
void capsule_pass2(const float* __restrict__ acc_ws, const float* __restrict__ ml_ws,
                   const float* __restrict__ lin_w, const float* __restrict__ lin_b,
                   float* __restrict__ p_out, float* __restrict__ v_out,
                   float* __restrict__ r_out)
{
    const int bc  = blockIdx.x;          // 0..B*C-1
    const int b   = bc / CC;
    const int c   = bc % CC;
    const int tid = threadIdx.x;

    __shared__ float s_w[SSEG];
    __shared__ float s_red[4];
    __shared__ float s_p;

    float mg = -INFINITY;
    for (int s = 0; s < SSEG; ++s)
        mg = fmaxf(mg, ml_ws[(((size_t)b * SSEG + s) * CC + c) * 2]);
    float lg = 0.0f;
    for (int s = 0; s < SSEG; ++s) {
        const float mw = ml_ws[(((size_t)b * SSEG + s) * CC + c) * 2];
        const float lw = ml_ws[(((size_t)b * SSEG + s) * CC + c) * 2 + 1];
        const float w  = __expf(mw - mg);
        lg += w * lw;
        if (tid == 0) s_w[s] = w;
    }
    __syncthreads();

    const float inv_l = 1.0f / lg;
    float v0 = 0.0f, v1 = 0.0f;
    for (int s = 0; s < SSEG; ++s) {
        const float* ap = acc_ws + (((size_t)b * SSEG + s) * CC + c) * DD;
        const float w = s_w[s];
        v0 = fmaf(w, ap[tid], v0);
        v1 = fmaf(w, ap[tid + 256], v1);
    }
    v0 *= inv_l;
    v1 *= inv_l;

    v_out[(size_t)bc * DD + tid]       = v0;
    v_out[(size_t)bc * DD + tid + 256] = v1;

    float part = v0 * lin_w[tid] + v1 * lin_w[tid + 256];
#pragma unroll
    for (int off = 1; off < 64; off <<= 1) part += __shfl_xor(part, off, 64);
    if ((tid & 63) == 0) s_red[tid >> 6] = part;
    __syncthreads();
    if (tid == 0) {
        const float dot = s_red[0] + s_red[1] + s_red[2] + s_red[3] + lin_b[0];
        const float p = tanhf(dot);
        s_p = p;
        p_out[bc] = p;
    }
    __syncthreads();
    const float p = s_p;
    r_out[(size_t)bc * DD + tid]       = p * v0;
    r_out[(size_t)bc * DD + tid + 256] = p * v1;
}

extern "C" void kernel_launch(void* const* d_in, const int* in_sizes, int n_in,
                              void* d_out, int out_size, void* d_ws, size_t ws_size,
                              hipStream_t stream) {
    const float* x   = (const float*)d_in[0];
    const float* Wa  = (const float*)d_in[1];
    const float* lw  = (const float*)d_in[2];
    const float* lb  = (const float*)d_in[3];

    float* out   = (float*)d_out;
    float* p_out = out;                       // (B, C)
    float* v_out = out + BB * CC;             // (B, C, D)
    float* r_out = v_out + BB * CC * DD;      // (B, C, D)

    float* acc_ws = (float*)d_ws;                           // B*SSEG*C*D floats
    float* ml_ws  = acc_ws + (size_t)BB * SSEG * CC * DD;   // B*SSEG*C*2 floats

    capsule_pass1<<<dim3(BB * SSEG), dim3(256), 0, stream>>>(x, Wa, acc_ws, ml_ws);
    capsule_pass2<<<dim3(BB * CC), dim3(256), 0, stream>>>(acc_ws, ml_ws, lw, lb,
                                                           p_out, v_out, r_out);
}

// Round 12
// 60.108 us; speedup vs baseline: 2.9501x; 1.0035x over previous
//
#include <hip/hip_runtime.h>
#include <math.h>

#define BB 32
#define NN 4096
#define DD 512
#define CC 5
#define SSEG 16   // 32*16 = 512 blocks = exactly 2 resident blocks/CU (launch_bounds 256,2)

// DPP-add step: v += dpp_permuted(v). bound_ctrl=1 -> 0 for lanes w/o source.
#define DPP_ADD(v, ctrl, rmask)                                                 \
    (v) += __int_as_float(__builtin_amdgcn_update_dpp(                          \
        0, __float_as_int(v), (ctrl), (rmask), 0xF, true))

// Canonical CDNA wave64 all-reduce via DPP only (no DS pipe), result made
// wave-uniform via readlane 63.
static __device__ __forceinline__ float wave_allreduce_add(float v)
{
    DPP_ADD(v, 0x111, 0xF);   // row_shr:1
    DPP_ADD(v, 0x112, 0xF);   // row_shr:2
    DPP_ADD(v, 0x114, 0xF);   // row_shr:4
    DPP_ADD(v, 0x118, 0xF);   // row_shr:8
    DPP_ADD(v, 0x142, 0xA);   // row_bcast:15 -> rows 1,3
    DPP_ADD(v, 0x143, 0xC);   // row_bcast:31 -> rows 2,3
    return __int_as_float(__builtin_amdgcn_readlane(__float_as_int(v), 63));
}

// Load one row into a named slot (two float4 = 8 VGPR). Macros take the two
// slot variables EXPLICITLY (no token pasting: `S##0.x` pastes against the
// pp-number `0.x` and fails). Named variables -> guaranteed reg residency.
#define LOADR(X0, X1, row)                                                      \
    {                                                                           \
        const float* _xr = xb_ + (size_t)(row) * DD;                            \
        X0 = *reinterpret_cast<const float4*>(_xr + d0);                        \
        X1 = *reinterpret_cast<const float4*>(_xr + d1);                        \
    }

// Process the row held in slot (X0,X1); if DOREL, reload the slot with row
// RROW right after the dot phase (slot regs dead from there on) so load issue
// is spread evenly across compute instead of bursting once per batch.
#define ROWSTEP(X0, X1, RROW, DOREL)                                            \
    {                                                                           \
        const float xv[8] = {X0.x, X0.y, X0.z, X0.w,                            \
                             X1.x, X1.y, X1.z, X1.w};                           \
        float e[CC];                                                            \
        _Pragma("unroll")                                                       \
        for (int _c = 0; _c < CC; ++_c) {                                       \
            float _s = 0.0f;                                                    \
            _Pragma("unroll")                                                   \
            for (int _j = 0; _j < 4; ++_j)                                      \
                _s = fmaf(xv[_j], wal[_j * CC + _c], _s);                       \
            _Pragma("unroll")                                                   \
            for (int _j = 0; _j < 4; ++_j)                                      \
                _s = fmaf(xv[4 + _j], wah[_j * CC + _c], _s);                   \
            e[_c] = _s;                                                         \
        }                                                                       \
        if (DOREL) { LOADR(X0, X1, (RROW)); }                                   \
        _Pragma("unroll")                                                       \
        for (int _c = 0; _c < CC; ++_c) e[_c] = wave_allreduce_add(e[_c]);      \
        bool _raise = false;                                                    \
        _Pragma("unroll")                                                       \
        for (int _c = 0; _c < CC; ++_c) _raise = _raise || (e[_c] > m[_c]);     \
        if (__ballot(_raise) != 0ull) {  /* wave-uniform branch */              \
            _Pragma("unroll")                                                   \
            for (int _c = 0; _c < CC; ++_c) {                                   \
                const float _mn = fmaxf(m[_c], e[_c]);                          \
                const float _sc = __expf(m[_c] - _mn);   /* 0 when m=-inf */    \
                l[_c] *= _sc;                                                   \
                _Pragma("unroll")                                               \
                for (int _j = 0; _j < 8; ++_j) acc[_c][_j] *= _sc;              \
                m[_c] = _mn;                                                    \
            }                                                                   \
        }                                                                       \
        _Pragma("unroll")                                                       \
        for (int _c = 0; _c < CC; ++_c) {                                       \
            const float _p = __expf(e[_c] - m[_c]);                             \
            l[_c] += _p;                                                        \
            _Pragma("unroll")                                                   \
            for (int _j = 0; _j < 8; ++_j)                                      \
                acc[_c][_j] = fmaf(_p, xv[_j], acc[_c][_j]);                    \
        }                                                                       \
    }

// Pass 1: stream x once. Block = (b, segment of 256 rows). 4 waves; each wave
// owns 64 contiguous rows, processed through a rotating 4-slot register
// pipeline: one row processed per step, its slot reloaded (row+4) mid-step.
__global__ __launch_bounds__(256, 2)
void capsule_pass1(const float* __restrict__ x, const float* __restrict__ Wa,
                   float* __restrict__ acc_ws, float* __restrict__ ml_ws)
{
    const int blk  = blockIdx.x;
    const int b    = blk / SSEG;
    const int seg  = blk % SSEG;
    const int tid  = threadIdx.x;
    const int lane = tid & 63;
    const int wid  = tid >> 6;   // 0..3

    const int d0 = lane * 4;
    const int d1 = 256 + lane * 4;

    // W_alpha fragments (4 d's x 5 c's per half), float4 loads
    float wal[20], wah[20];
    {
        const float4* pl = reinterpret_cast<const float4*>(Wa + d0 * CC);
        const float4* ph = reinterpret_cast<const float4*>(Wa + d1 * CC);
#pragma unroll
        for (int q = 0; q < 5; ++q) {
            float4 a = pl[q];
            wal[q * 4 + 0] = a.x; wal[q * 4 + 1] = a.y;
            wal[q * 4 + 2] = a.z; wal[q * 4 + 3] = a.w;
            float4 b4 = ph[q];
            wah[q * 4 + 0] = b4.x; wah[q * 4 + 1] = b4.y;
            wah[q * 4 + 2] = b4.z; wah[q * 4 + 3] = b4.w;
        }
    }

    float acc[CC][8];
    float m[CC], l[CC];
#pragma unroll
    for (int c = 0; c < CC; ++c) {
        m[c] = -INFINITY;
        l[c] = 0.0f;
#pragma unroll
        for (int j = 0; j < 8; ++j) acc[c][j] = 0.0f;
    }

    // segment = 256 rows; wave slice = 64 contiguous rows
    const int rs  = seg * (NN / SSEG);
    const int ws_ = rs + wid * (NN / SSEG / 4);
    const int we_ = ws_ + (NN / SSEG / 4);

    const float* xb_ = x + (size_t)b * NN * DD;

    // rotating 4-slot pipeline
    float4 sA0, sA1, sB0, sB1, sC0, sC1, sD0, sD1;
    LOADR(sA0, sA1, ws_ + 0);
    LOADR(sB0, sB1, ws_ + 1);
    LOADR(sC0, sC1, ws_ + 2);
    LOADR(sD0, sD1, ws_ + 3);

    int i = ws_;
    for (; i + 4 < we_; i += 4) {
        ROWSTEP(sA0, sA1, i + 4, 1);
        ROWSTEP(sB0, sB1, i + 5, 1);
        ROWSTEP(sC0, sC1, i + 6, 1);
        ROWSTEP(sD0, sD1, i + 7, 1);
    }
    // tail: slots hold rows we_-4 .. we_-1; no reloads
    ROWSTEP(sA0, sA1, 0, 0);
    ROWSTEP(sB0, sB1, 0, 0);
    ROWSTEP(sC0, sC1, 0, 0);
    ROWSTEP(sD0, sD1, 0, 0);

    // ---- combine the 4 waves ----
    __shared__ float s_ml[4][CC][2];
    __shared__ float s_acc[CC][DD];   // 10 KB

    if (lane == 0) {
#pragma unroll
        for (int c = 0; c < CC; ++c) {
            s_ml[wid][c][0] = m[c];
            s_ml[wid][c][1] = l[c];
        }
    }
    __syncthreads();

    float mb2[CC], lb2[CC], cw[CC];
#pragma unroll
    for (int c = 0; c < CC; ++c) {
        float mm = s_ml[0][c][0];
#pragma unroll
        for (int w = 1; w < 4; ++w) mm = fmaxf(mm, s_ml[w][c][0]);
        mb2[c] = mm;
        float ll = 0.0f;
#pragma unroll
        for (int w = 0; w < 4; ++w) ll += __expf(s_ml[w][c][0] - mm) * s_ml[w][c][1];
        lb2[c] = ll;
        cw[c] = __expf(s_ml[wid][c][0] - mm);
    }

    for (int w = 0; w < 4; ++w) {
        if (wid == w) {
#pragma unroll
            for (int c = 0; c < CC; ++c) {
#pragma unroll
                for (int j = 0; j < 8; ++j) {
                    const int d = (j < 4) ? (d0 + j) : (d1 + j - 4);
                    const float v = acc[c][j] * cw[c];
                    if (w == 0) s_acc[c][d] = v;
                    else        s_acc[c][d] += v;
                }
            }
        }
        __syncthreads();
    }

    // write block partials to workspace (float4)
    float4* accp = reinterpret_cast<float4*>(acc_ws + (size_t)blk * CC * DD);
    const float4* sa = reinterpret_cast<const float4*>(&s_acc[0][0]);
    for (int idx = tid; idx < CC * DD / 4; idx += 256) accp[idx] = sa[idx];
    if (tid < CC) {
        ml_ws[((size_t)blk * CC + tid) * 2 + 0] = mb2[tid];
        ml_ws[((size_t)blk * CC + tid) * 2 + 1] = lb2[tid];
    }
}

// Pass 2: one block per (b,c). Combine SSEG segment partials, normalize,
// epilogue p = tanh(v.w + b), r = p*v, write all three outputs.
__global__ __launch_bounds__(256)
void capsule_pass2(const float* __restrict__ acc_ws, const float* __restrict__ ml_ws,
                   const float* __restrict__ lin_w, const float* __restrict__ lin_b,
                   float* __restrict__ p_out, float* __restrict__ v_out,
                   float* __restrict__ r_out)
{
    const int bc  = blockIdx.x;          // 0..B*C-1
    const int b   = bc / CC;
    const int c   = bc % CC;
    const int tid = threadIdx.x;

    __shared__ float s_w[SSEG];
    __shared__ float s_red[4];
    __shared__ float s_p;

    float mg = -INFINITY;
    for (int s = 0; s < SSEG; ++s)
        mg = fmaxf(mg, ml_ws[(((size_t)b * SSEG + s) * CC + c) * 2]);
    float lg = 0.0f;
    for (int s = 0; s < SSEG; ++s) {
        const float mw = ml_ws[(((size_t)b * SSEG + s) * CC + c) * 2];
        const float lw = ml_ws[(((size_t)b * SSEG + s) * CC + c) * 2 + 1];
        const float w  = __expf(mw - mg);
        lg += w * lw;
        if (tid == 0) s_w[s] = w;
    }
    __syncthreads();

    const float inv_l = 1.0f / lg;
    float v0 = 0.0f, v1 = 0.0f;
    for (int s = 0; s < SSEG; ++s) {
        const float* ap = acc_ws + (((size_t)b * SSEG + s) * CC + c) * DD;
        const float w = s_w[s];
        v0 = fmaf(w, ap[tid], v0);
        v1 = fmaf(w, ap[tid + 256], v1);
    }
    v0 *= inv_l;
    v1 *= inv_l;

    v_out[(size_t)bc * DD + tid]       = v0;
    v_out[(size_t)bc * DD + tid + 256] = v1;

    float part = v0 * lin_w[tid] + v1 * lin_w[tid + 256];
#pragma unroll
    for (int off = 1; off < 64; off <<= 1) part += __shfl_xor(part, off, 64);
    if ((tid & 63) == 0) s_red[tid >> 6] = part;
    __syncthreads();
    if (tid == 0) {
        const float dot = s_red[0] + s_red[1] + s_red[2] + s_red[3] + lin_b[0];
        const float p = tanhf(dot);
        s_p = p;
        p_out[bc] = p;
    }
    __syncthreads();
    const float p = s_p;
    r_out[(size_t)bc * DD + tid]       = p * v0;
    r_out[(size_t)bc * DD + tid + 256] = p * v1;
}

extern "C" void kernel_launch(void* const* d_in, const int* in_sizes, int n_in,
                              void* d_out, int out_size, void* d_ws, size_t ws_size,
                              hipStream_t stream) {
    const float* x   = (const float*)d_in[0];
    const float* Wa  = (const float*)d_in[1];
    const float* lw  = (const float*)d_in[2];
    const float* lb  = (const float*)d_in[3];

    float* out   = (float*)d_out;
    float* p_out = out;                       // (B, C)
    float* v_out = out + BB * CC;             // (B, C, D)
    float* r_out = v_out + BB * CC * DD;      // (B, C, D)

    float* acc_ws = (float*)d_ws;                           // B*SSEG*C*D floats
    float* ml_ws  = acc_ws + (size_t)BB * SSEG * CC * DD;   // B*SSEG*C*2 floats

    capsule_pass1<<<dim3(BB * SSEG), dim3(256), 0, stream>>>(x, Wa, acc_ws, ml_ws);
    capsule_pass2<<<dim3(BB * CC), dim3(256), 0, stream>>>(acc_ws, ml_ws, lw, lb,
                                                           p_out, v_out, r_out);
}

// Round 13
// 56.176 us; speedup vs baseline: 3.1566x; 1.0700x over previous
//
#include <hip/hip_runtime.h>
#include <math.h>

#define BB 32
#define NN 4096
#define DD 512
#define CC 5
#define SSEG 16   // 32*16 = 512 blocks = exactly 2 resident blocks/CU (launch_bounds 256,2)

// DPP-add step: v += dpp_permuted(v). bound_ctrl=1 -> 0 for lanes w/o source.
#define DPP_ADD(v, ctrl, rmask)                                                 \
    (v) += __int_as_float(__builtin_amdgcn_update_dpp(                          \
        0, __float_as_int(v), (ctrl), (rmask), 0xF, true))

// Canonical CDNA wave64 all-reduce via DPP only (no DS pipe), result made
// wave-uniform via readlane 63.
static __device__ __forceinline__ float wave_allreduce_add(float v)
{
    DPP_ADD(v, 0x111, 0xF);   // row_shr:1
    DPP_ADD(v, 0x112, 0xF);   // row_shr:2
    DPP_ADD(v, 0x114, 0xF);   // row_shr:4
    DPP_ADD(v, 0x118, 0xF);   // row_shr:8
    DPP_ADD(v, 0x142, 0xA);   // row_bcast:15 -> rows 1,3
    DPP_ADD(v, 0x143, 0xC);   // row_bcast:31 -> rows 2,3
    return __int_as_float(__builtin_amdgcn_readlane(__float_as_int(v), 63));
}

// Hot-loop bodies as macros over kernel-scope arrays, fully unrolled
// compile-time indices -> guaranteed VGPR residency (R6/R8 lesson).
#define LOADB(XA, XB, row)                                                      \
    {                                                                           \
        _Pragma("unroll")                                                       \
        for (int _r = 0; _r < 4; ++_r) {                                        \
            const float* _xr = xb_ + (size_t)((row) + _r) * DD;                 \
            XA[_r] = *reinterpret_cast<const float4*>(_xr + d0);                \
            XB[_r] = *reinterpret_cast<const float4*>(_xr + d1);                \
        }                                                                       \
    }

#define PROCB(XA, XB)                                                           \
    {                                                                           \
        float _e[4][CC];                                                        \
        _Pragma("unroll")                                                       \
        for (int _r = 0; _r < 4; ++_r) {                                        \
            const float _xv[8] = {XA[_r].x, XA[_r].y, XA[_r].z, XA[_r].w,       \
                                  XB[_r].x, XB[_r].y, XB[_r].z, XB[_r].w};      \
            _Pragma("unroll")                                                   \
            for (int _c = 0; _c < CC; ++_c) {                                   \
                float _s = 0.0f;                                                \
                _Pragma("unroll")                                               \
                for (int _j = 0; _j < 4; ++_j)                                  \
                    _s = fmaf(_xv[_j], wal[_j * CC + _c], _s);                  \
                _Pragma("unroll")                                               \
                for (int _j = 0; _j < 4; ++_j)                                  \
                    _s = fmaf(_xv[4 + _j], wah[_j * CC + _c], _s);              \
                _e[_r][_c] = _s;                                                \
            }                                                                   \
        }                                                                       \
        _Pragma("unroll")                                                       \
        for (int _r = 0; _r < 4; ++_r)                                          \
            _Pragma("unroll")                                                   \
            for (int _c = 0; _c < CC; ++_c)                                     \
                _e[_r][_c] = wave_allreduce_add(_e[_r][_c]);                    \
        float _mb[CC];                                                          \
        _Pragma("unroll")                                                       \
        for (int _c = 0; _c < CC; ++_c)                                         \
            _mb[_c] = fmaxf(fmaxf(_e[0][_c], _e[1][_c]),                        \
                            fmaxf(_e[2][_c], _e[3][_c]));                       \
        bool _raise = false;                                                    \
        _Pragma("unroll")                                                       \
        for (int _c = 0; _c < CC; ++_c) _raise = _raise || (_mb[_c] > m[_c]);   \
        if (__ballot(_raise) != 0ull) {                                         \
            _Pragma("unroll")                                                   \
            for (int _c = 0; _c < CC; ++_c) {                                   \
                const float _mn = fmaxf(m[_c], _mb[_c]);                        \
                const float _sc = __expf(m[_c] - _mn);                          \
                l[_c] *= _sc;                                                   \
                _Pragma("unroll")                                               \
                for (int _j = 0; _j < 8; ++_j) acc[_c][_j] *= _sc;              \
                m[_c] = _mn;                                                    \
            }                                                                   \
        }                                                                       \
        _Pragma("unroll")                                                       \
        for (int _r = 0; _r < 4; ++_r) {                                        \
            const float _xv[8] = {XA[_r].x, XA[_r].y, XA[_r].z, XA[_r].w,       \
                                  XB[_r].x, XB[_r].y, XB[_r].z, XB[_r].w};      \
            _Pragma("unroll")                                                   \
            for (int _c = 0; _c < CC; ++_c) {                                   \
                const float _p = __expf(_e[_r][_c] - m[_c]);                    \
                l[_c] += _p;                                                    \
                _Pragma("unroll")                                               \
                for (int _j = 0; _j < 8; ++_j)                                  \
                    acc[_c][_j] = fmaf(_p, _xv[_j], acc[_c][_j]);               \
            }                                                                   \
        }                                                                       \
    }

// Pass 1 (R7 verbatim, best measured 57.8us): ping-pong double-buffered 4-row
// batches, peeled tail, 2 blocks/CU.
__global__ __launch_bounds__(256, 2)
void capsule_pass1(const float* __restrict__ x, const float* __restrict__ Wa,
                   float* __restrict__ acc_ws, float* __restrict__ ml_ws)
{
    const int blk  = blockIdx.x;
    const int b    = blk / SSEG;
    const int seg  = blk % SSEG;
    const int tid  = threadIdx.x;
    const int lane = tid & 63;
    const int wid  = tid >> 6;   // 0..3

    const int d0 = lane * 4;
    const int d1 = 256 + lane * 4;

    float wal[20], wah[20];
    {
        const float4* pl = reinterpret_cast<const float4*>(Wa + d0 * CC);
        const float4* ph = reinterpret_cast<const float4*>(Wa + d1 * CC);
#pragma unroll
        for (int q = 0; q < 5; ++q) {
            float4 a = pl[q];
            wal[q * 4 + 0] = a.x; wal[q * 4 + 1] = a.y;
            wal[q * 4 + 2] = a.z; wal[q * 4 + 3] = a.w;
            float4 b4 = ph[q];
            wah[q * 4 + 0] = b4.x; wah[q * 4 + 1] = b4.y;
            wah[q * 4 + 2] = b4.z; wah[q * 4 + 3] = b4.w;
        }
    }

    float acc[CC][8];
    float m[CC], l[CC];
#pragma unroll
    for (int c = 0; c < CC; ++c) {
        m[c] = -INFINITY;
        l[c] = 0.0f;
#pragma unroll
        for (int j = 0; j < 8; ++j) acc[c][j] = 0.0f;
    }

    const int rs  = seg * (NN / SSEG);
    const int ws_ = rs + wid * (NN / SSEG / 4);
    const int we_ = ws_ + (NN / SSEG / 4);

    const float* xb_ = x + (size_t)b * NN * DD;

    float4 xaA[4], xbA[4], xaB[4], xbB[4];
    LOADB(xaA, xbA, ws_);
    int i0 = ws_;
    for (; i0 + 8 < we_; i0 += 8) {        // last pair peeled (no dead prefetch)
        LOADB(xaB, xbB, i0 + 4);
        PROCB(xaA, xbA);
        LOADB(xaA, xbA, i0 + 8);
        PROCB(xaB, xbB);
    }
    LOADB(xaB, xbB, i0 + 4);
    PROCB(xaA, xbA);
    PROCB(xaB, xbB);

    // ---- combine the 4 waves ----
    __shared__ float s_ml[4][CC][2];
    __shared__ float s_acc[CC][DD];   // 10 KB

    if (lane == 0) {
#pragma unroll
        for (int c = 0; c < CC; ++c) {
            s_ml[wid][c][0] = m[c];
            s_ml[wid][c][1] = l[c];
        }
    }
    __syncthreads();

    float mb2[CC], lb2[CC], cw[CC];
#pragma unroll
    for (int c = 0; c < CC; ++c) {
        float mm = s_ml[0][c][0];
#pragma unroll
        for (int w = 1; w < 4; ++w) mm = fmaxf(mm, s_ml[w][c][0]);
        mb2[c] = mm;
        float ll = 0.0f;
#pragma unroll
        for (int w = 0; w < 4; ++w) ll += __expf(s_ml[w][c][0] - mm) * s_ml[w][c][1];
        lb2[c] = ll;
        cw[c] = __expf(s_ml[wid][c][0] - mm);
    }

    for (int w = 0; w < 4; ++w) {
        if (wid == w) {
#pragma unroll
            for (int c = 0; c < CC; ++c) {
#pragma unroll
                for (int j = 0; j < 8; ++j) {
                    const int d = (j < 4) ? (d0 + j) : (d1 + j - 4);
                    const float v = acc[c][j] * cw[c];
                    if (w == 0) s_acc[c][d] = v;
                    else        s_acc[c][d] += v;
                }
            }
        }
        __syncthreads();
    }

    float4* accp = reinterpret_cast<float4*>(acc_ws + (size_t)blk * CC * DD);
    const float4* sa = reinterpret_cast<const float4*>(&s_acc[0][0]);
    for (int idx = tid; idx < CC * DD / 4; idx += 256) accp[idx] = sa[idx];
    if (tid < CC) {
        ml_ws[((size_t)blk * CC + tid) * 2 + 0] = mb2[tid];
        ml_ws[((size_t)blk * CC + tid) * 2 + 1] = lb2[tid];
    }
}

// Pass 2 (restructured): one block per (b,c), 512 threads, one d per thread.
// All 16 segment loads independent & fully unrolled (16-deep MLP), weights
// folded to w[s]*inv_l once. Wave-DPP + LDS for the lin_w dot.
__global__ __launch_bounds__(512)
void capsule_pass2(const float* __restrict__ acc_ws, const float* __restrict__ ml_ws,
                   const float* __restrict__ lin_w, const float* __restrict__ lin_b,
                   float* __restrict__ p_out, float* __restrict__ v_out,
                   float* __restrict__ r_out)
{
    const int bc  = blockIdx.x;          // 0..B*C-1
    const int b   = bc / CC;
    const int c   = bc % CC;
    const int tid = threadIdx.x;         // 0..511 = d index
    const int lane = tid & 63;
    const int wid  = tid >> 6;           // 0..7

    __shared__ float s_red[8];
    __shared__ float s_p;

    // all threads redundantly compute the (identical) segment weights
    float mg = -INFINITY;
#pragma unroll
    for (int s = 0; s < SSEG; ++s)
        mg = fmaxf(mg, ml_ws[(((size_t)b * SSEG + s) * CC + c) * 2]);
    float lg = 0.0f;
    float w[SSEG];
#pragma unroll
    for (int s = 0; s < SSEG; ++s) {
        const float mw = ml_ws[(((size_t)b * SSEG + s) * CC + c) * 2];
        const float lw = ml_ws[(((size_t)b * SSEG + s) * CC + c) * 2 + 1];
        w[s] = __expf(mw - mg);
        lg += w[s] * lw;
    }
    const float inv_l = 1.0f / lg;
#pragma unroll
    for (int s = 0; s < SSEG; ++s) w[s] *= inv_l;

    // 16 independent loads (one per segment), then weighted sum
    const float* ap0 = acc_ws + (((size_t)b * SSEG) * CC + c) * DD + tid;
    float xs[SSEG];
#pragma unroll
    for (int s = 0; s < SSEG; ++s)
        xs[s] = ap0[(size_t)s * CC * DD];
    float v = 0.0f;
#pragma unroll
    for (int s = 0; s < SSEG; ++s)
        v = fmaf(w[s], xs[s], v);

    v_out[(size_t)bc * DD + tid] = v;

    // dot(v, lin_w) across 512 threads: DPP wave-reduce + LDS combine
    float part = v * lin_w[tid];
    DPP_ADD(part, 0x111, 0xF);
    DPP_ADD(part, 0x112, 0xF);
    DPP_ADD(part, 0x114, 0xF);
    DPP_ADD(part, 0x118, 0xF);
    DPP_ADD(part, 0x142, 0xA);
    DPP_ADD(part, 0x143, 0xC);
    if (lane == 63) s_red[wid] = part;
    __syncthreads();
    if (tid == 0) {
        float dot = lin_b[0];
#pragma unroll
        for (int q = 0; q < 8; ++q) dot += s_red[q];
        s_p = tanhf(dot);
        p_out[bc] = s_p;
    }
    __syncthreads();
    r_out[(size_t)bc * DD + tid] = s_p * v;
}

extern "C" void kernel_launch(void* const* d_in, const int* in_sizes, int n_in,
                              void* d_out, int out_size, void* d_ws, size_t ws_size,
                              hipStream_t stream) {
    const float* x   = (const float*)d_in[0];
    const float* Wa  = (const float*)d_in[1];
    const float* lw  = (const float*)d_in[2];
    const float* lb  = (const float*)d_in[3];

    float* out   = (float*)d_out;
    float* p_out = out;                       // (B, C)
    float* v_out = out + BB * CC;             // (B, C, D)
    float* r_out = v_out + BB * CC * DD;      // (B, C, D)

    float* acc_ws = (float*)d_ws;                           // B*SSEG*C*D floats
    float* ml_ws  = acc_ws + (size_t)BB * SSEG * CC * DD;   // B*SSEG*C*2 floats

    capsule_pass1<<<dim3(BB * SSEG), dim3(256), 0, stream>>>(x, Wa, acc_ws, ml_ws);
    capsule_pass2<<<dim3(BB * CC), dim3(512), 0, stream>>>(acc_ws, ml_ws, lw, lb,
                                                           p_out, v_out, r_out);
}